// Round 5
// baseline (281.560 us; speedup 1.0000x reference)
//
#include <hip/hip_runtime.h>

typedef __bf16 bf16_t;
typedef __bf16 bf16x4 __attribute__((ext_vector_type(4)));
typedef __bf16 bf16x8 __attribute__((ext_vector_type(8)));
typedef float f32x4 __attribute__((ext_vector_type(4)));

#define NB 4        // batch
#define SS 2048     // seq
#define DM 1024     // d_model
#define NH 16       // heads
#define DK 64       // d_kv
#define MM (NB*SS)  // 8192 rows
#define LOG2E 1.44269504f

// ---------------- fused prep: convert H, transpose weights, bias table ----------------
__global__ __launch_bounds__(256) void k_prep(
    const float* __restrict__ H, bf16_t* __restrict__ Hbf,
    const float* __restrict__ W0, const float* __restrict__ W1,
    const float* __restrict__ W2, const float* __restrict__ W3,
    bf16_t* __restrict__ T0, bf16_t* __restrict__ T1,
    bf16_t* __restrict__ T2, bf16_t* __restrict__ T3,
    const float* __restrict__ rel_emb, float* __restrict__ biasT) {
  __shared__ float t[64][65];
  const int blk = blockIdx.x, tid = threadIdx.x;
  if (blk < 8192) {
    int i = blk * 256 + tid;
    float4 v = ((const float4*)H)[i];
    bf16x4 o = {(bf16_t)v.x, (bf16_t)v.y, (bf16_t)v.z, (bf16_t)v.w};
    *(bf16x4*)(Hbf + 4 * (size_t)i) = o;
  } else if (blk < 9216) {
    int tt = blk - 8192;
    int which = tt >> 8, rem = tt & 255;
    int k0 = (rem >> 4) * 64, n0 = (rem & 15) * 64;
    const float* W = which == 0 ? W0 : which == 1 ? W1 : which == 2 ? W2 : W3;
    bf16_t* T = which == 0 ? T0 : which == 1 ? T1 : which == 2 ? T2 : T3;
#pragma unroll
    for (int i = 0; i < 16; i++) {
      int idx = tid + i * 256; int r = idx >> 6, c = idx & 63;
      t[r][c] = W[(size_t)(k0 + r) * DM + n0 + c];
    }
    __syncthreads();
#pragma unroll
    for (int i = 0; i < 16; i++) {
      int idx = tid + i * 256; int r = idx >> 6, c = idx & 63;
      T[(size_t)(n0 + r) * DM + k0 + c] = (bf16_t)t[c][r];
    }
  } else {
    int tt = (blk - 9216) * 256 + tid;
    if (tt < 2 * SS - 1) {
      int rel = tt - (SS - 1);     // rel = j - i
      int n = -rel;
      int ret = 0;
      if (n < 0) { ret = 16; n = -n; }
      int bucket;
      if (n < 8) bucket = n;
      else {
        int v = 8 + (int)(logf((float)n * 0.125f) * (8.0f / logf(16.0f)));
        bucket = v < 15 ? v : 15;
      }
      bucket += ret;
#pragma unroll
      for (int h = 0; h < NH; h++)
        biasT[h * (2 * SS - 1) + tt] = rel_emb[bucket * NH + h] * LOG2E;
    }
  }
}

// ---------------- async 16B global -> LDS (lane i deposits at lds_base + 16*i) -------------
__device__ __forceinline__ void gld16(const bf16_t* g, bf16_t* l) {
  __builtin_amdgcn_global_load_lds(
      (const __attribute__((address_space(1))) unsigned int*)g,
      (__attribute__((address_space(3))) unsigned int*)l, 16, 0, 0);
}

#define VMC(n) asm volatile("s_waitcnt vmcnt(" #n ")" ::: "memory")
#define SBAR() do { __builtin_amdgcn_sched_barrier(0); __builtin_amdgcn_s_barrier(); } while (0)

// ---------------- 256x256-tile 8-phase GEMM mainloop (T2+T3+T4+T5) ----------------
// 512 threads = 8 waves (2M x 4N), per-wave C = 128x64. BK=64, K=1024 fixed (16 K-tiles,
// 8 iterations x 2 tiles). LDS 128KB: [2 buf][2 half][128x64] per operand.
// T2: row-XOR swizzle byte^=(row&7)<<4, inverse-applied on the gld16 GLOBAL source
//     (linear LDS dest), applied on ds_read -> ~2-way conflicts instead of 16-way.
// T3/T4: per phase stage exactly 1 half-tile (2 gld16/thread); counted vmcnt only at
//     ends of ph1/ph5 (vmcnt(6)) and ph3/ph7 (vmcnt(4)); every guarded load has >=3
//     phases of slack. Stage map (iter computes tiles t=even->buf0 @ph0-3, t+1->buf1
//     @ph4-7): ph0 B0(t+1) ph1 B1(t+1) ph2 A1(t+1) ph3 A0(t+2) ph4 B0(t+2)
//     ph5 B1(t+2) ph6 A1(t+2) ph7 A0(t+3); each region staged right after its last
//     reader's barrier, 2 tiles before its next read.
// T5: setprio(1) around the 16-MFMA cluster.
__device__ __forceinline__ void gemm256(const bf16_t* __restrict__ A,
                                        const bf16_t* __restrict__ Bt,
                                        const int m0, const int n0,
                                        bf16_t* ldsA, bf16_t* ldsB,
                                        f32x4 (&acc)[8][4]) {
  const int tid = threadIdx.x;
  const int lane = tid & 63, l15 = lane & 15, quad = lane >> 4;
  const int wave = tid >> 6;
  const int wvu = __builtin_amdgcn_readfirstlane(wave);
  const int wm2 = wave >> 2, wn4 = wave & 3;
  const f32x4 z4 = {0.f, 0.f, 0.f, 0.f};
#pragma unroll
  for (int i = 0; i < 8; i++)
#pragma unroll
    for (int j = 0; j < 4; j++) acc[i][j] = z4;

  // stage one 128x64 half-tile (16KB): linear LDS dest, inverse-swizzled global source
  auto stage = [&](const bf16_t* G, int gr0, int k0, bf16_t* dstbase) {
#pragma unroll
    for (int j = 0; j < 2; j++) {
      const int L = wvu * 2048 + j * 1024 + lane * 16;   // byte offset in half-tile
      const int row = L >> 7;                            // 128B per row
      const int colb = (L & 127) ^ ((row & 7) << 4);
      gld16(G + (size_t)(gr0 + row) * DM + k0 + (colb >> 1),
            dstbase + ((wvu * 2048 + j * 1024) >> 1));
    }
  };

#define STGA(tt, hf, bb) if ((tt) < 16) stage(A, m0 + (hf) * 128, (tt) * 64, \
                                              ldsA + ((bb) * 2 + (hf)) * 8192)
#define STGB(tt, hf, bb) if ((tt) < 16) stage(Bt, n0 + (hf) * 128, (tt) * 64, \
                                              ldsB + ((bb) * 2 + (hf)) * 8192)

  // prologue: tile0 fully + A-half0 of tile1; wait tile0 (newest 2 loads may fly)
  STGA(0, 0, 0); STGA(0, 1, 0); STGB(0, 0, 0); STGB(0, 1, 0); STGA(1, 0, 1);
  VMC(2);
  SBAR();

#define PHASE(bb, mh, nh, STG_STMT, VMSTMT)                                              \
  {                                                                                      \
    bf16x8 af[4][2], bfr[2][2];                                                          \
    _Pragma("unroll") for (int mi = 0; mi < 4; mi++)                                     \
    _Pragma("unroll") for (int kk = 0; kk < 2; kk++) {                                   \
      const int ml = wm2 * 128 + (mh) * 64 + mi * 16 + l15;                              \
      const int row = ml & 127;                                                          \
      const int cb = (kk * 64 + quad * 16) ^ ((row & 7) << 4);                           \
      af[mi][kk] = *(const bf16x8*)(ldsA + ((bb) * 2 + (ml >> 7)) * 8192 +               \
                                    row * 64 + (cb >> 1));                               \
    }                                                                                    \
    _Pragma("unroll") for (int ni = 0; ni < 2; ni++)                                     \
    _Pragma("unroll") for (int kk = 0; kk < 2; kk++) {                                   \
      const int nl = wn4 * 64 + (nh) * 32 + ni * 16 + l15;                               \
      const int row = nl & 127;                                                          \
      const int cb = (kk * 64 + quad * 16) ^ ((row & 7) << 4);                           \
      bfr[ni][kk] = *(const bf16x8*)(ldsB + ((bb) * 2 + (nl >> 7)) * 8192 +              \
                                     row * 64 + (cb >> 1));                              \
    }                                                                                    \
    STG_STMT;                                                                            \
    SBAR();                                                                              \
    __builtin_amdgcn_s_setprio(1);                                                       \
    _Pragma("unroll") for (int mi = 0; mi < 4; mi++)                                     \
    _Pragma("unroll") for (int ni = 0; ni < 2; ni++) {                                   \
      acc[(mh) * 4 + mi][(nh) * 2 + ni] = __builtin_amdgcn_mfma_f32_16x16x32_bf16(       \
          af[mi][0], bfr[ni][0], acc[(mh) * 4 + mi][(nh) * 2 + ni], 0, 0, 0);            \
      acc[(mh) * 4 + mi][(nh) * 2 + ni] = __builtin_amdgcn_mfma_f32_16x16x32_bf16(       \
          af[mi][1], bfr[ni][1], acc[(mh) * 4 + mi][(nh) * 2 + ni], 0, 0, 0);            \
    }                                                                                    \
    __builtin_amdgcn_s_setprio(0);                                                       \
    VMSTMT;                                                                              \
    SBAR();                                                                              \
  }

  for (int it2 = 0; it2 < 8; ++it2) {
    const int t = 2 * it2;
    PHASE(0, 0, 0, STGB(t + 1, 0, 1), );
    PHASE(0, 0, 1, STGB(t + 1, 1, 1), VMC(6));
    PHASE(0, 1, 0, STGA(t + 1, 1, 1), );
    PHASE(0, 1, 1, STGA(t + 2, 0, 0), VMC(4));
    PHASE(1, 0, 0, STGB(t + 2, 0, 0), );
    PHASE(1, 0, 1, STGB(t + 2, 1, 0), VMC(6));
    PHASE(1, 1, 0, STGA(t + 2, 1, 0), );
    PHASE(1, 1, 1, STGA(t + 3, 0, 1), VMC(4));
  }
#undef PHASE
#undef STGA
#undef STGB
}

// ---------------- fused QKV projection: one 8192x3072 GEMM (Wqt|Wkt|Wvt contiguous) -------
// grid 384 blocks (32 m-panels x 12 n-panels), m fastest within each XCD chunk so the
// 512KB B-panel stays L2-hot. Each wave's 64-col slice = exactly one head; `which`
// (Q/K/V) is block-uniform. Epilogue formulas identical to the verified R0 stores.
__global__ __launch_bounds__(512, 1) void k_gemm_qkv(
    const bf16_t* __restrict__ A, const bf16_t* __restrict__ Wt,
    bf16_t* __restrict__ Q, bf16_t* __restrict__ Kf, bf16_t* __restrict__ Vf) {
  __shared__ bf16_t ldsA[4 * 8192];   // 64 KB
  __shared__ bf16_t ldsB[4 * 8192];   // 64 KB
  const int lin = blockIdx.x;
  const int id = (lin & 7) * 48 + (lin >> 3);   // bijective XCD chunking (384 % 8 == 0)
  const int np = id >> 5, mp = id & 31;
  const int m0 = mp * 256, n0 = np * 256;
  f32x4 acc[8][4];
  gemm256(A, Wt, m0, n0, ldsA, ldsB, acc);

  const int tid = threadIdx.x;
  const int lane = tid & 63, l15 = lane & 15, quad = lane >> 4;
  const int wave = tid >> 6;
  const int wm = (wave >> 2) * 128, wn = (wave & 3) * 64;
  const int ng = n0 + wn;             // 64-aligned global n; one head per wave
  const int which = ng >> 10;
  const int h = (ng & 1023) >> 6;
  const int mb = m0 + wm;
  const int b = mb >> 11;             // 128 rows stay within one batch
  const int sb = mb & (SS - 1);

  if (which == 0) {
#pragma unroll
    for (int ig = 0; ig < 8; ig++)
#pragma unroll
      for (int jg = 0; jg < 4; jg++) {
        const int d = jg * 16 + l15;
#pragma unroll
        for (int r = 0; r < 4; r++) {
          const int s = sb + ig * 16 + quad * 4 + r;
          Q[(((size_t)(b * NH + h)) * SS + s) * DK + d] = (bf16_t)(acc[ig][jg][r] * LOG2E);
        }
      }
  } else if (which == 1) {
#pragma unroll
    for (int ig = 0; ig < 8; ig++)
#pragma unroll
      for (int jg = 0; jg < 4; jg++) {
        const int d = jg * 16 + l15;
#pragma unroll
        for (int r = 0; r < 4; r++) {
          const int s = sb + ig * 16 + quad * 4 + r;
          const int slot = 4 * ((s >> 5) & 1) + 2 * ((s >> 2) & 1) + (d >> 5);
          const int fl = ((d >> 3) & 3) * 16 + 4 * ((s >> 3) & 3) + (s & 3);
          Kf[(((size_t)(b * NH + h) * 32 + (s >> 6)) * 8 + slot) * 512 + fl * 8 + (d & 7)] =
              (bf16_t)acc[ig][jg][r];
        }
      }
  } else {
#pragma unroll
    for (int ig = 0; ig < 8; ig++)
#pragma unroll
      for (int jg = 0; jg < 4; jg++) {
        const int s = sb + ig * 16 + quad * 4;   // 4 consecutive s, 4-aligned
        const int d = jg * 16 + l15;
        const int slot = 4 * ((s >> 5) & 1) + (d >> 4);
        const int fl = ((s >> 3) & 3) * 16 + (d & 15);
        bf16x4 pk = {(bf16_t)acc[ig][jg][0], (bf16_t)acc[ig][jg][1],
                     (bf16_t)acc[ig][jg][2], (bf16_t)acc[ig][jg][3]};
        *(bf16x4*)(&Vf[(((size_t)(b * NH + h) * 32 + (s >> 6)) * 8 + slot) * 512 +
                       fl * 8 + (s & 7)]) = pk;
      }
  }
}

// ---------------- m97-style GEMM mainloop: C[128x128] = A[MxK] * Bt[NxK]^T ----------------
__device__ __forceinline__ void gemm_tile(const bf16_t* __restrict__ A,
                                          const bf16_t* __restrict__ Bt, const int K,
                                          const int m0, const int n0,
                                          bf16_t* As, bf16_t* Bs, f32x4 (&acc)[4][4]) {
  const int tid = threadIdx.x;
  const int lane = tid & 63, wave = tid >> 6;
  const int l15 = lane & 15, quad = lane >> 4;
  const int wm = (wave >> 1) * 64, wn = (wave & 1) * 64;
  const int wwu = __builtin_amdgcn_readfirstlane(wave);
  const f32x4 z4 = {0.f, 0.f, 0.f, 0.f};
#pragma unroll
  for (int i = 0; i < 4; i++)
#pragma unroll
    for (int j = 0; j < 4; j++) acc[i][j] = z4;

  const int rr = lane >> 2;
  const int cc = (lane & 3) * 8;
  for (int k0 = 0; k0 < K; k0 += 32) {
    __syncthreads();
    gld16(A + (size_t)(m0 + wwu * 32 + rr) * K + k0 + cc,       As + wwu * 1024);
    gld16(A + (size_t)(m0 + wwu * 32 + 16 + rr) * K + k0 + cc,  As + wwu * 1024 + 512);
    gld16(Bt + (size_t)(n0 + wwu * 32 + rr) * K + k0 + cc,      Bs + wwu * 1024);
    gld16(Bt + (size_t)(n0 + wwu * 32 + 16 + rr) * K + k0 + cc, Bs + wwu * 1024 + 512);
    __syncthreads();
    bf16x8 af[4], bfr[4];
#pragma unroll
    for (int i = 0; i < 4; i++) {
      af[i]  = *(const bf16x8*)(As + (wm + i * 16 + l15) * 32 + quad * 8);
      bfr[i] = *(const bf16x8*)(Bs + (wn + i * 16 + l15) * 32 + quad * 8);
    }
#pragma unroll
    for (int i = 0; i < 4; i++)
#pragma unroll
      for (int j = 0; j < 4; j++)
        acc[i][j] = __builtin_amdgcn_mfma_f32_16x16x32_bf16(af[i], bfr[j], acc[i][j], 0, 0, 0);
  }
}

// ---------------- flash attention (R3 version: T15 pipeline, no setprio) ---------
__global__ __launch_bounds__(256, 2) void k_attn(const bf16_t* __restrict__ Qg,
                                                 const bf16_t* __restrict__ Kf,
                                                 const bf16_t* __restrict__ Vf,
                                                 const float* __restrict__ biasT,
                                                 bf16_t* __restrict__ ctx) {
  const int lin = blockIdx.x + 16 * blockIdx.y;      // 1024 blocks, x fastest
  const int nid = (lin & 7) * 128 + (lin >> 3);      // bijective XCD chunking
  const int bh = nid >> 4;
  const int it0 = (nid & 15) * 128;
  const int b = bh >> 4, h = bh & 15;
  const bf16_t* Qp = Qg + ((size_t)bh * SS + it0) * DK;
  const float* biasH = biasT + h * (2 * SS - 1);

  __shared__ float bias2[512][2];         // diag-band: bias2[w] = {B(w-256), B(w-255)}
  __shared__ float OsumS[2][4][16];       // per (qh, mi, qrow) partial denominators
  __shared__ f32x4 Ored[2 * 4 * 4 * 64];  // 32 KB cross-wave O partials

  const int tid = threadIdx.x;
  const int lane = tid & 63, wave = tid >> 6;
  const int l15 = lane & 15, quad = lane >> 4;
  const int kh = wave & 1, qh = wave >> 1;

  for (int w = tid; w < 512; w += 256) {
    int g = w - 256 + (SS - 1);
    bias2[w][0] = biasH[g];
    bias2[w][1] = biasH[g + 1];
  }
  const float Bpos = biasH[(SS - 1) + 1024];   // rel >= 128: saturated bucket 31
  const float Bneg = biasH[(SS - 1) - 1024];   // rel <= -128: saturated bucket 15

  const bf16_t* KfB = Kf + (size_t)bh * 32 * 4096 + lane * 8;
  const bf16_t* VfB = Vf + (size_t)bh * 32 * 4096 + lane * 8;
  auto loadK = [&](int it, bf16x8 (&kf)[2][2]) {
    const bf16_t* kb = KfB + (size_t)it * 4096;
#pragma unroll
    for (int t = 0; t < 2; t++)
#pragma unroll
      for (int hf = 0; hf < 2; hf++)
        kf[t][hf] = *(const bf16x8*)(kb + ((2 * kh + t) * 2 + hf) * 512);
  };
  auto loadV = [&](int it, bf16x8 (&vf)[4]) {
    const bf16_t* vb = VfB + (size_t)it * 4096;
#pragma unroll
    for (int ni = 0; ni < 4; ni++)
      vf[ni] = *(const bf16x8*)(vb + (kh * 4 + ni) * 512);
  };

  bf16x8 qf[4][2];
#pragma unroll
  for (int mi = 0; mi < 4; mi++) {
    const bf16_t* qr = Qp + (size_t)(64 * qh + mi * 16 + l15) * DK + quad * 8;
    qf[mi][0] = *(const bf16x8*)qr;
    qf[mi][1] = *(const bf16x8*)(qr + 32);
  }

  f32x4 accO[4][4], accS[4];
  const f32x4 z4 = {0.f, 0.f, 0.f, 0.f};
#pragma unroll
  for (int mi = 0; mi < 4; mi++) {
    accS[mi] = z4;
#pragma unroll
    for (int ni = 0; ni < 4; ni++) accO[mi][ni] = z4;
  }
  const bf16_t one = (bf16_t)1.0f;
  const bf16x8 ones = {one, one, one, one, one, one, one, one};

  const int wb0 = 32 * kh + 8 * quad - 64 * qh - l15 - it0 + 256;

  // QK(it) + exp2 -> pfC; PV(it-1) from pfP/vfP interleaved per-mi (fills QK latency).
  auto step = [&](int it, bf16x8 (&kfC)[2][2], bf16x8 (&pfP)[4], bf16x8 (&vfP)[4],
                  bf16x8 (&pfC)[4]) {
    const int diff = it * 64 - it0;
    const bool band = (diff >= -128) && (diff < 256);
    const float cconst = diff >= 256 ? Bpos : Bneg;
    const f32x4 csplat = {cconst, cconst, cconst, cconst};
    const int jb = it * 64 + wb0;
#pragma unroll
    for (int mi = 0; mi < 4; mi++) {
      f32x4 c0, c1;
      if (band) {
        const int w = jb - mi * 16;
        float2 a0 = *(const float2*)bias2[w],     b0 = *(const float2*)bias2[w + 2];
        float2 a1 = *(const float2*)bias2[w + 4], b1 = *(const float2*)bias2[w + 6];
        c0 = f32x4{a0.x, a0.y, b0.x, b0.y};
        c1 = f32x4{a1.x, a1.y, b1.x, b1.y};
      } else {
        c0 = csplat;
        c1 = csplat;
      }
      f32x4 s0 = __builtin_amdgcn_mfma_f32_16x16x32_bf16(
          kfC[0][1], qf[mi][1],
          __builtin_amdgcn_mfma_f32_16x16x32_bf16(kfC[0][0], qf[mi][0], c0, 0, 0, 0), 0, 0, 0);
      f32x4 s1 = __builtin_amdgcn_mfma_f32_16x16x32_bf16(
          kfC[1][1], qf[mi][1],
          __builtin_amdgcn_mfma_f32_16x16x32_bf16(kfC[1][0], qf[mi][0], c1, 0, 0, 0), 0, 0, 0);
      // PV of previous tile, same mi: independent of s0/s1 -> scheduler fills QK latency
#pragma unroll
      for (int ni = 0; ni < 4; ni++)
        accO[mi][ni] =
            __builtin_amdgcn_mfma_f32_16x16x32_bf16(vfP[ni], pfP[mi], accO[mi][ni], 0, 0, 0);
      accS[mi] = __builtin_amdgcn_mfma_f32_16x16x32_bf16(ones, pfP[mi], accS[mi], 0, 0, 0);
      pfC[mi] =
          bf16x8{(bf16_t)__builtin_amdgcn_exp2f(s0[0]), (bf16_t)__builtin_amdgcn_exp2f(s0[1]),
                 (bf16_t)__builtin_amdgcn_exp2f(s0[2]), (bf16_t)__builtin_amdgcn_exp2f(s0[3]),
                 (bf16_t)__builtin_amdgcn_exp2f(s1[0]), (bf16_t)__builtin_amdgcn_exp2f(s1[1]),
                 (bf16_t)__builtin_amdgcn_exp2f(s1[2]), (bf16_t)__builtin_amdgcn_exp2f(s1[3])};
    }
  };
  // tile 0: QK + exp only (no previous tile)
  auto step0 = [&](bf16x8 (&kfC)[2][2], bf16x8 (&pfC)[4]) {
    const int diff = -it0;
    const bool band = (diff >= -128) && (diff < 256);
    const float cconst = diff >= 256 ? Bpos : Bneg;
    const f32x4 csplat = {cconst, cconst, cconst, cconst};
    const int jb = wb0;
#pragma unroll
    for (int mi = 0; mi < 4; mi++) {
      f32x4 c0, c1;
      if (band) {
        const int w = jb - mi * 16;
        float2 a0 = *(const float2*)bias2[w],     b0 = *(const float2*)bias2[w + 2];
        float2 a1 = *(const float2*)bias2[w + 4], b1 = *(const float2*)bias2[w + 6];
        c0 = f32x4{a0.x, a0.y, b0.x, b0.y};
        c1 = f32x4{a1.x, a1.y, b1.x, b1.y};
      } else {
        c0 = csplat;
        c1 = csplat;
      }
      f32x4 s0 = __builtin_amdgcn_mfma_f32_16x16x32_bf16(
          kfC[0][1], qf[mi][1],
          __builtin_amdgcn_mfma_f32_16x16x32_bf16(kfC[0][0], qf[mi][0], c0, 0, 0, 0), 0, 0, 0);
      f32x4 s1 = __builtin_amdgcn_mfma_f32_16x16x32_bf16(
          kfC[1][1], qf[mi][1],
          __builtin_amdgcn_mfma_f32_16x16x32_bf16(kfC[1][0], qf[mi][0], c1, 0, 0, 0), 0, 0, 0);
      pfC[mi] =
          bf16x8{(bf16_t)__builtin_amdgcn_exp2f(s0[0]), (bf16_t)__builtin_amdgcn_exp2f(s0[1]),
                 (bf16_t)__builtin_amdgcn_exp2f(s0[2]), (bf16_t)__builtin_amdgcn_exp2f(s0[3]),
                 (bf16_t)__builtin_amdgcn_exp2f(s1[0]), (bf16_t)__builtin_amdgcn_exp2f(s1[1]),
                 (bf16_t)__builtin_amdgcn_exp2f(s1[2]), (bf16_t)__builtin_amdgcn_exp2f(s1[3])};
    }
  };

  bf16x8 kfA[2][2], vfA[4], kfB[2][2], vfB[4], pfA[4], pfB[4];
  loadK(0, kfA);
  loadV(0, vfA);
  __syncthreads();  // bias2 ready
  loadK(1, kfB);
  step0(kfA, pfA);      // QK(0) -> pfA
  loadV(1, vfB);

  for (int it = 1; it < 32; it += 2) {
    // odd it: cur = B buffers, prev = A
    if (it + 1 < 32) loadK(it + 1, kfA);   // kfA dead since QK(it-1)
    step(it, kfB, pfA, vfA, pfB);          // QK(it); PV(it-1) consumes vfA
    if (it + 1 < 32) {
      loadV(it + 1, vfA);                  // vfA dead now
      loadK(it + 2, kfB);                  // it+2 <= 31 whenever this branch runs
      step(it + 1, kfA, pfB, vfB, pfA);    // QK(it+1); PV(it) consumes vfB
      loadV(it + 2, vfB);
    }
  }
  // PV for the last tile (31): pfB produced by step(31), vfB holds vf(31)
#pragma unroll
  for (int mi = 0; mi < 4; mi++) {
#pragma unroll
    for (int ni = 0; ni < 4; ni++)
      accO[mi][ni] =
          __builtin_amdgcn_mfma_f32_16x16x32_bf16(vfB[ni], pfB[mi], accO[mi][ni], 0, 0, 0);
    accS[mi] = __builtin_amdgcn_mfma_f32_16x16x32_bf16(ones, pfB[mi], accS[mi], 0, 0, 0);
  }

  __syncthreads();
  if (kh) {
#pragma unroll
    for (int mi = 0; mi < 4; mi++) {
#pragma unroll
      for (int ni = 0; ni < 4; ni++)
        Ored[((qh * 4 + mi) * 4 + ni) * 64 + lane] = accO[mi][ni];
      if (quad == 0) OsumS[qh][mi][l15] = accS[mi][0];
    }
  }
  __syncthreads();
  if (!kh) {
#pragma unroll
    for (int mi = 0; mi < 4; mi++) {
      float l = accS[mi][0] + OsumS[qh][mi][l15];
      float inv = 1.0f / l;
      int srow = it0 + 64 * qh + mi * 16 + l15;
#pragma unroll
      for (int ni = 0; ni < 4; ni++) {
        f32x4 o = accO[mi][ni] + Ored[((qh * 4 + mi) * 4 + ni) * 64 + lane];
        bf16x4 pk = {(bf16_t)(o[0] * inv), (bf16_t)(o[1] * inv),
                     (bf16_t)(o[2] * inv), (bf16_t)(o[3] * inv)};
        *(bf16x4*)(&ctx[((size_t)(b * SS + srow)) * DM + h * DK + ni * 16 + quad * 4]) = pk;
      }
    }
  }
}

// ---------------- output projection: out = ctx @ Wo (fp32 out), m-panel-fastest grid ------
__global__ __launch_bounds__(256) void k_gemm_out(const bf16_t* __restrict__ A,
                                                  const bf16_t* __restrict__ Wot,
                                                  float* __restrict__ out) {
  __shared__ bf16_t As[128 * 32];
  __shared__ bf16_t Bs[128 * 32];
  const int m0 = blockIdx.x * 128, n0 = blockIdx.y * 128;
  f32x4 acc[4][4];
  gemm_tile(A, Wot, DM, m0, n0, As, Bs, acc);

  const int tid = threadIdx.x;
  const int lane = tid & 63, wave = tid >> 6;
  const int l15 = lane & 15, quad = lane >> 4;
  const int wm = (wave >> 1) * 64, wn = (wave & 1) * 64;
#pragma unroll
  for (int i = 0; i < 4; i++)
#pragma unroll
    for (int j = 0; j < 4; j++)
#pragma unroll
      for (int r = 0; r < 4; r++) {
        int m = m0 + wm + i * 16 + quad * 4 + r;
        int n = n0 + wn + j * 16 + l15;
        out[(size_t)m * DM + n] = acc[i][j][r];
      }
}

extern "C" void kernel_launch(void* const* d_in, const int* in_sizes, int n_in,
                              void* d_out, int out_size, void* d_ws, size_t ws_size,
                              hipStream_t stream) {
  (void)in_sizes; (void)n_in; (void)out_size; (void)ws_size;
  const float* H  = (const float*)d_in[0];
  const float* Wq = (const float*)d_in[1];
  const float* Wk = (const float*)d_in[2];
  const float* Wv = (const float*)d_in[3];
  const float* Wo = (const float*)d_in[4];
  const float* rel = (const float*)d_in[5];
  float* out = (float*)d_out;

  char* w = (char*)d_ws;
  bf16_t* Hbf = (bf16_t*)w; w += (size_t)MM * DM * 2;
  bf16_t* Wqt = (bf16_t*)w; w += (size_t)DM * DM * 2;   // Wqt|Wkt|Wvt contiguous:
  bf16_t* Wkt = (bf16_t*)w; w += (size_t)DM * DM * 2;   // fused B matrix [3072][1024]
  bf16_t* Wvt = (bf16_t*)w; w += (size_t)DM * DM * 2;
  bf16_t* Wot = (bf16_t*)w; w += (size_t)DM * DM * 2;
  bf16_t* Q   = (bf16_t*)w; w += (size_t)MM * DM * 2;
  bf16_t* Kf  = (bf16_t*)w; w += (size_t)MM * DM * 2;
  bf16_t* Vf  = (bf16_t*)w; w += (size_t)MM * DM * 2;
  bf16_t* CTX = (bf16_t*)w; w += (size_t)MM * DM * 2;
  float* biasT = (float*)w;  // NH * 4095 floats

  k_prep<<<9232, 256, 0, stream>>>(H, Hbf, Wq, Wk, Wv, Wo, Wqt, Wkt, Wvt, Wot, rel, biasT);
  k_gemm_qkv<<<384, 512, 0, stream>>>(Hbf, Wqt, Q, Kf, Vf);
  k_attn<<<dim3(SS / 128, NB * NH), 256, 0, stream>>>(Q, Kf, Vf, biasT, CTX);
  k_gemm_out<<<dim3(MM / 128, DM / 128), 256, 0, stream>>>(CTX, Wot, out);
}

// Round 7
// 261.970 us; speedup vs baseline: 1.0748x; 1.0748x over previous
//
#include <hip/hip_runtime.h>

typedef __bf16 bf16_t;
typedef __bf16 bf16x4 __attribute__((ext_vector_type(4)));
typedef __bf16 bf16x8 __attribute__((ext_vector_type(8)));
typedef float f32x4 __attribute__((ext_vector_type(4)));

#define NB 4        // batch
#define SS 2048     // seq
#define DM 1024     // d_model
#define NH 16       // heads
#define DK 64       // d_kv
#define MM (NB*SS)  // 8192 rows
#define LOG2E 1.44269504f

#define VMC(n) asm volatile("s_waitcnt vmcnt(" #n ")" ::: "memory")
#define LGKM0() asm volatile("s_waitcnt lgkmcnt(0)" ::: "memory")

// fragment-major index for weight matrices consumed as MFMA B-operands:
// element (n,k) -> ((n>>4)*32 + (k>>5))*512 + ((n&15) + ((k>>3)&3)*16)*8 + (k&7)
// so a wave's 16x32 fragment (rows n0..n0+15, k0..k0+31) is one contiguous 1KB block,
// lane (l15 + 16*quad) holding its 16B at lane*8.
__device__ __forceinline__ int fidx(int n, int k) {
  return ((n >> 4) * 32 + (k >> 5)) * 512 + ((n & 15) + ((k >> 3) & 3) * 16) * 8 + (k & 7);
}

// ---------------- fused prep: convert H, transpose weights, bias table ----------------
// Wq/Wk/Wv transposed into FRAGMENT-MAJOR (for k_gemm_qkv's direct B streams);
// Wo stays row-major [n][k] (k_gemm_out still stages it through LDS).
__global__ __launch_bounds__(256) void k_prep(
    const float* __restrict__ H, bf16_t* __restrict__ Hbf,
    const float* __restrict__ W0, const float* __restrict__ W1,
    const float* __restrict__ W2, const float* __restrict__ W3,
    bf16_t* __restrict__ T0, bf16_t* __restrict__ T1,
    bf16_t* __restrict__ T2, bf16_t* __restrict__ T3,
    const float* __restrict__ rel_emb, float* __restrict__ biasT) {
  __shared__ float t[64][65];
  const int blk = blockIdx.x, tid = threadIdx.x;
  if (blk < 8192) {
    int i = blk * 256 + tid;
    float4 v = ((const float4*)H)[i];
    bf16x4 o = {(bf16_t)v.x, (bf16_t)v.y, (bf16_t)v.z, (bf16_t)v.w};
    *(bf16x4*)(Hbf + 4 * (size_t)i) = o;
  } else if (blk < 9216) {
    int tt = blk - 8192;
    int which = tt >> 8, rem = tt & 255;
    int k0 = (rem >> 4) * 64, n0 = (rem & 15) * 64;
    const float* W = which == 0 ? W0 : which == 1 ? W1 : which == 2 ? W2 : W3;
    bf16_t* T = which == 0 ? T0 : which == 1 ? T1 : which == 2 ? T2 : T3;
#pragma unroll
    for (int i = 0; i < 16; i++) {
      int idx = tid + i * 256; int r = idx >> 6, c = idx & 63;
      t[r][c] = W[(size_t)(k0 + r) * DM + n0 + c];
    }
    __syncthreads();
    if (which < 3) {
#pragma unroll
      for (int i = 0; i < 16; i++) {
        int idx = tid + i * 256; int r = idx >> 6, c = idx & 63;
        T[fidx(n0 + r, k0 + c)] = (bf16_t)t[c][r];   // value = W[k0+c][n0+r]
      }
    } else {
#pragma unroll
      for (int i = 0; i < 16; i++) {
        int idx = tid + i * 256; int r = idx >> 6, c = idx & 63;
        T[(size_t)(n0 + r) * DM + k0 + c] = (bf16_t)t[c][r];
      }
    }
  } else {
    int tt = (blk - 9216) * 256 + tid;
    if (tt < 2 * SS - 1) {
      int rel = tt - (SS - 1);     // rel = j - i
      int n = -rel;
      int ret = 0;
      if (n < 0) { ret = 16; n = -n; }
      int bucket;
      if (n < 8) bucket = n;
      else {
        int v = 8 + (int)(logf((float)n * 0.125f) * (8.0f / logf(16.0f)));
        bucket = v < 15 ? v : 15;
      }
      bucket += ret;
#pragma unroll
      for (int h = 0; h < NH; h++)
        biasT[h * (2 * SS - 1) + tt] = rel_emb[bucket * NH + h] * LOG2E;
    }
  }
}

// ---------------- async 16B global -> LDS (lane i deposits at lds_base + 16*i) -------------
__device__ __forceinline__ void gld16(const bf16_t* g, bf16_t* l) {
  __builtin_amdgcn_global_load_lds(
      (const __attribute__((address_space(1))) unsigned int*)g,
      (__attribute__((address_space(3))) unsigned int*)l, 16, 0, 0);
}

// ---------------- m97-style GEMM mainloop: C[128x128] = A[MxK] * Bt[NxK]^T ----------------
__device__ __forceinline__ void gemm_tile(const bf16_t* __restrict__ A,
                                          const bf16_t* __restrict__ Bt, const int K,
                                          const int m0, const int n0,
                                          bf16_t* As, bf16_t* Bs, f32x4 (&acc)[4][4]) {
  const int tid = threadIdx.x;
  const int lane = tid & 63, wave = tid >> 6;
  const int l15 = lane & 15, quad = lane >> 4;
  const int wm = (wave >> 1) * 64, wn = (wave & 1) * 64;
  const int wwu = __builtin_amdgcn_readfirstlane(wave);
  const f32x4 z4 = {0.f, 0.f, 0.f, 0.f};
#pragma unroll
  for (int i = 0; i < 4; i++)
#pragma unroll
    for (int j = 0; j < 4; j++) acc[i][j] = z4;

  const int rr = lane >> 2;
  const int cc = (lane & 3) * 8;
  for (int k0 = 0; k0 < K; k0 += 32) {
    __syncthreads();
    gld16(A + (size_t)(m0 + wwu * 32 + rr) * K + k0 + cc,       As + wwu * 1024);
    gld16(A + (size_t)(m0 + wwu * 32 + 16 + rr) * K + k0 + cc,  As + wwu * 1024 + 512);
    gld16(Bt + (size_t)(n0 + wwu * 32 + rr) * K + k0 + cc,      Bs + wwu * 1024);
    gld16(Bt + (size_t)(n0 + wwu * 32 + 16 + rr) * K + k0 + cc, Bs + wwu * 1024 + 512);
    __syncthreads();
    bf16x8 af[4], bfr[4];
#pragma unroll
    for (int i = 0; i < 4; i++) {
      af[i]  = *(const bf16x8*)(As + (wm + i * 16 + l15) * 32 + quad * 8);
      bfr[i] = *(const bf16x8*)(Bs + (wn + i * 16 + l15) * 32 + quad * 8);
    }
#pragma unroll
    for (int i = 0; i < 4; i++)
#pragma unroll
      for (int j = 0; j < 4; j++)
        acc[i][j] = __builtin_amdgcn_mfma_f32_16x16x32_bf16(af[i], bfr[j], acc[i][j], 0, 0, 0);
  }
}

// ---------------- QKV projection: A via LDS, B fragment-direct from global ----------------
// B (weights) is fragment-major (k_prep): each wave streams its 4 B-fragments per K-step
// straight to VGPRs (register ping-pong, 1 K-step slack), B-panel L2-resident under the
// m-fastest grid. Barriers are raw s_barrier with manual counts so the B prefetch never
// drains: loop-top needs only lgkmcnt(0); post-stage needs vmcnt(4) (the 2 gld16 A-loads
// are issued BEFORE the 4 B loads -- order pinned by sched_barrier -- so vmcnt(4) means
// "A landed, B still flying"). The same VMC(4) also proves the PREVIOUS B prefetch
// retired (FIFO: it is older than the gld16 pair), so bc/bn are always ready for MFMA.
__global__ __launch_bounds__(256) void k_gemm_qkv(
    const bf16_t* __restrict__ A, const bf16_t* __restrict__ Wqt,
    const bf16_t* __restrict__ Wkt, const bf16_t* __restrict__ Wvt,
    bf16_t* __restrict__ Q, bf16_t* __restrict__ Kf, bf16_t* __restrict__ Vf) {
  __shared__ bf16_t As[128 * 32];
  const int which = blockIdx.z;
  const bf16_t* Bf = which == 0 ? Wqt : (which == 1 ? Wkt : Wvt);
  const int m0 = blockIdx.x * 128, n0 = blockIdx.y * 128;
  const int tid = threadIdx.x;
  const int lane = tid & 63, wave = tid >> 6;
  const int l15 = lane & 15, quad = lane >> 4;
  const int wm = (wave >> 1) * 64, wn = (wave & 1) * 64;
  const int wwu = __builtin_amdgcn_readfirstlane(wave);
  const int rr = lane >> 2, cc = (lane & 3) * 8;

  const bf16_t* Bb = Bf + ((n0 + wn) >> 4) * 16384 + lane * 8;  // + j*16384 + ks*512
  const bf16_t* Arow0 = A + (size_t)(m0 + wwu * 32 + rr) * DM + cc;
  const bf16_t* Arow1 = Arow0 + (size_t)16 * DM;

  f32x4 acc[4][4];
  const f32x4 z4 = {0.f, 0.f, 0.f, 0.f};
#pragma unroll
  for (int i = 0; i < 4; i++)
#pragma unroll
    for (int j = 0; j < 4; j++) acc[i][j] = z4;

  bf16x8 bc[4], bn[4];
#pragma unroll
  for (int j = 0; j < 4; j++) bc[j] = *(const bf16x8*)(Bb + j * 16384);

  for (int it2 = 0; it2 < 16; ++it2) {
    const int t = 2 * it2;
    // ---- even K-step t: stage A(t), prefetch B(t+1), compute with bc ----
    LGKM0();                                    // my ds_reads of As done
    __builtin_amdgcn_sched_barrier(0);
    __builtin_amdgcn_s_barrier();               // all waves done reading As
    gld16(Arow0 + t * 32, As + wwu * 1024);
    gld16(Arow1 + t * 32, As + wwu * 1024 + 512);
    __builtin_amdgcn_sched_barrier(0);          // pin order: gld16 BEFORE B loads
#pragma unroll
    for (int j = 0; j < 4; j++) bn[j] = *(const bf16x8*)(Bb + j * 16384 + (t + 1) * 512);
    VMC(4);                                     // A landed; 4 B loads still in flight
    __builtin_amdgcn_sched_barrier(0);
    __builtin_amdgcn_s_barrier();
    {
      bf16x8 af[4];
#pragma unroll
      for (int i = 0; i < 4; i++)
        af[i] = *(const bf16x8*)(As + (wm + i * 16 + l15) * 32 + quad * 8);
#pragma unroll
      for (int i = 0; i < 4; i++)
#pragma unroll
        for (int j = 0; j < 4; j++)
          acc[i][j] = __builtin_amdgcn_mfma_f32_16x16x32_bf16(af[i], bc[j], acc[i][j], 0, 0, 0);
    }
    // ---- odd K-step t+1: stage A(t+1), prefetch B(t+2), compute with bn ----
    LGKM0();
    __builtin_amdgcn_sched_barrier(0);
    __builtin_amdgcn_s_barrier();
    gld16(Arow0 + (t + 1) * 32, As + wwu * 1024);
    gld16(Arow1 + (t + 1) * 32, As + wwu * 1024 + 512);
    __builtin_amdgcn_sched_barrier(0);
    if (it2 < 15) {
#pragma unroll
      for (int j = 0; j < 4; j++) bc[j] = *(const bf16x8*)(Bb + j * 16384 + (t + 2) * 512);
      VMC(4);
    } else {
      VMC(0);
    }
    __builtin_amdgcn_sched_barrier(0);
    __builtin_amdgcn_s_barrier();
    {
      bf16x8 af[4];
#pragma unroll
      for (int i = 0; i < 4; i++)
        af[i] = *(const bf16x8*)(As + (wm + i * 16 + l15) * 32 + quad * 8);
#pragma unroll
      for (int i = 0; i < 4; i++)
#pragma unroll
        for (int j = 0; j < 4; j++)
          acc[i][j] = __builtin_amdgcn_mfma_f32_16x16x32_bf16(af[i], bn[j], acc[i][j], 0, 0, 0);
    }
  }

  // epilogue: proven R0 store formulas
  if (which == 0) {
#pragma unroll
    for (int i = 0; i < 4; i++)
#pragma unroll
      for (int j = 0; j < 4; j++)
#pragma unroll
        for (int r = 0; r < 4; r++) {
          int m = m0 + wm + i * 16 + quad * 4 + r;
          int n = n0 + wn + j * 16 + l15;
          int b = m >> 11, s = m & (SS - 1);
          int h = n >> 6, d = n & 63;
          Q[(((size_t)(b * NH + h)) * SS + s) * DK + d] = (bf16_t)(acc[i][j][r] * LOG2E);
        }
  } else if (which == 1) {
#pragma unroll
    for (int i = 0; i < 4; i++)
#pragma unroll
      for (int j = 0; j < 4; j++)
#pragma unroll
        for (int r = 0; r < 4; r++) {
          int m = m0 + wm + i * 16 + quad * 4 + r;
          int n = n0 + wn + j * 16 + l15;
          int b = m >> 11, s = m & (SS - 1);
          int h = n >> 6, d = n & 63;
          int slot = 4 * ((s >> 5) & 1) + 2 * ((s >> 2) & 1) + (d >> 5);
          int fl = ((d >> 3) & 3) * 16 + 4 * ((s >> 3) & 3) + (s & 3);
          Kf[(((size_t)(b * NH + h) * 32 + (s >> 6)) * 8 + slot) * 512 + fl * 8 + (d & 7)] =
              (bf16_t)acc[i][j][r];
        }
  } else {
#pragma unroll
    for (int i = 0; i < 4; i++)
#pragma unroll
      for (int j = 0; j < 4; j++) {
        int m = m0 + wm + i * 16 + quad * 4;   // 4 consecutive s, 4-aligned
        int n = n0 + wn + j * 16 + l15;
        int b = m >> 11, s = m & (SS - 1);
        int h = n >> 6, d = n & 63;
        int slot = 4 * ((s >> 5) & 1) + (d >> 4);
        int fl = ((s >> 3) & 3) * 16 + (d & 15);
        bf16x4 pk = {(bf16_t)acc[i][j][0], (bf16_t)acc[i][j][1],
                     (bf16_t)acc[i][j][2], (bf16_t)acc[i][j][3]};
        *(bf16x4*)(&Vf[(((size_t)(b * NH + h) * 32 + (s >> 6)) * 8 + slot) * 512 +
                       fl * 8 + (s & 7)]) = pk;
      }
  }
}

// ---------------- flash attention (R3 version: T15 pipeline, no setprio) ---------
__global__ __launch_bounds__(256, 2) void k_attn(const bf16_t* __restrict__ Qg,
                                                 const bf16_t* __restrict__ Kf,
                                                 const bf16_t* __restrict__ Vf,
                                                 const float* __restrict__ biasT,
                                                 bf16_t* __restrict__ ctx) {
  const int lin = blockIdx.x + 16 * blockIdx.y;      // 1024 blocks, x fastest
  const int nid = (lin & 7) * 128 + (lin >> 3);      // bijective XCD chunking
  const int bh = nid >> 4;
  const int it0 = (nid & 15) * 128;
  const int b = bh >> 4, h = bh & 15;
  const bf16_t* Qp = Qg + ((size_t)bh * SS + it0) * DK;
  const float* biasH = biasT + h * (2 * SS - 1);

  __shared__ float bias2[512][2];         // diag-band: bias2[w] = {B(w-256), B(w-255)}
  __shared__ float OsumS[2][4][16];       // per (qh, mi, qrow) partial denominators
  __shared__ f32x4 Ored[2 * 4 * 4 * 64];  // 32 KB cross-wave O partials

  const int tid = threadIdx.x;
  const int lane = tid & 63, wave = tid >> 6;
  const int l15 = lane & 15, quad = lane >> 4;
  const int kh = wave & 1, qh = wave >> 1;

  for (int w = tid; w < 512; w += 256) {
    int g = w - 256 + (SS - 1);
    bias2[w][0] = biasH[g];
    bias2[w][1] = biasH[g + 1];
  }
  const float Bpos = biasH[(SS - 1) + 1024];   // rel >= 128: saturated bucket 31
  const float Bneg = biasH[(SS - 1) - 1024];   // rel <= -128: saturated bucket 15

  const bf16_t* KfB = Kf + (size_t)bh * 32 * 4096 + lane * 8;
  const bf16_t* VfB = Vf + (size_t)bh * 32 * 4096 + lane * 8;
  auto loadK = [&](int it, bf16x8 (&kf)[2][2]) {
    const bf16_t* kb = KfB + (size_t)it * 4096;
#pragma unroll
    for (int t = 0; t < 2; t++)
#pragma unroll
      for (int hf = 0; hf < 2; hf++)
        kf[t][hf] = *(const bf16x8*)(kb + ((2 * kh + t) * 2 + hf) * 512);
  };
  auto loadV = [&](int it, bf16x8 (&vf)[4]) {
    const bf16_t* vb = VfB + (size_t)it * 4096;
#pragma unroll
    for (int ni = 0; ni < 4; ni++)
      vf[ni] = *(const bf16x8*)(vb + (kh * 4 + ni) * 512);
  };

  bf16x8 qf[4][2];
#pragma unroll
  for (int mi = 0; mi < 4; mi++) {
    const bf16_t* qr = Qp + (size_t)(64 * qh + mi * 16 + l15) * DK + quad * 8;
    qf[mi][0] = *(const bf16x8*)qr;
    qf[mi][1] = *(const bf16x8*)(qr + 32);
  }

  f32x4 accO[4][4], accS[4];
  const f32x4 z4 = {0.f, 0.f, 0.f, 0.f};
#pragma unroll
  for (int mi = 0; mi < 4; mi++) {
    accS[mi] = z4;
#pragma unroll
    for (int ni = 0; ni < 4; ni++) accO[mi][ni] = z4;
  }
  const bf16_t one = (bf16_t)1.0f;
  const bf16x8 ones = {one, one, one, one, one, one, one, one};

  const int wb0 = 32 * kh + 8 * quad - 64 * qh - l15 - it0 + 256;

  // QK(it) + exp2 -> pfC; PV(it-1) from pfP/vfP interleaved per-mi (fills QK latency).
  auto step = [&](int it, bf16x8 (&kfC)[2][2], bf16x8 (&pfP)[4], bf16x8 (&vfP)[4],
                  bf16x8 (&pfC)[4]) {
    const int diff = it * 64 - it0;
    const bool band = (diff >= -128) && (diff < 256);
    const float cconst = diff >= 256 ? Bpos : Bneg;
    const f32x4 csplat = {cconst, cconst, cconst, cconst};
    const int jb = it * 64 + wb0;
#pragma unroll
    for (int mi = 0; mi < 4; mi++) {
      f32x4 c0, c1;
      if (band) {
        const int w = jb - mi * 16;
        float2 a0 = *(const float2*)bias2[w],     b0 = *(const float2*)bias2[w + 2];
        float2 a1 = *(const float2*)bias2[w + 4], b1 = *(const float2*)bias2[w + 6];
        c0 = f32x4{a0.x, a0.y, b0.x, b0.y};
        c1 = f32x4{a1.x, a1.y, b1.x, b1.y};
      } else {
        c0 = csplat;
        c1 = csplat;
      }
      f32x4 s0 = __builtin_amdgcn_mfma_f32_16x16x32_bf16(
          kfC[0][1], qf[mi][1],
          __builtin_amdgcn_mfma_f32_16x16x32_bf16(kfC[0][0], qf[mi][0], c0, 0, 0, 0), 0, 0, 0);
      f32x4 s1 = __builtin_amdgcn_mfma_f32_16x16x32_bf16(
          kfC[1][1], qf[mi][1],
          __builtin_amdgcn_mfma_f32_16x16x32_bf16(kfC[1][0], qf[mi][0], c1, 0, 0, 0), 0, 0, 0);
      // PV of previous tile, same mi: independent of s0/s1 -> scheduler fills QK latency
#pragma unroll
      for (int ni = 0; ni < 4; ni++)
        accO[mi][ni] =
            __builtin_amdgcn_mfma_f32_16x16x32_bf16(vfP[ni], pfP[mi], accO[mi][ni], 0, 0, 0);
      accS[mi] = __builtin_amdgcn_mfma_f32_16x16x32_bf16(ones, pfP[mi], accS[mi], 0, 0, 0);
      pfC[mi] =
          bf16x8{(bf16_t)__builtin_amdgcn_exp2f(s0[0]), (bf16_t)__builtin_amdgcn_exp2f(s0[1]),
                 (bf16_t)__builtin_amdgcn_exp2f(s0[2]), (bf16_t)__builtin_amdgcn_exp2f(s0[3]),
                 (bf16_t)__builtin_amdgcn_exp2f(s1[0]), (bf16_t)__builtin_amdgcn_exp2f(s1[1]),
                 (bf16_t)__builtin_amdgcn_exp2f(s1[2]), (bf16_t)__builtin_amdgcn_exp2f(s1[3])};
    }
  };
  // tile 0: QK + exp only (no previous tile)
  auto step0 = [&](bf16x8 (&kfC)[2][2], bf16x8 (&pfC)[4]) {
    const int diff = -it0;
    const bool band = (diff >= -128) && (diff < 256);
    const float cconst = diff >= 256 ? Bpos : Bneg;
    const f32x4 csplat = {cconst, cconst, cconst, cconst};
    const int jb = wb0;
#pragma unroll
    for (int mi = 0; mi < 4; mi++) {
      f32x4 c0, c1;
      if (band) {
        const int w = jb - mi * 16;
        float2 a0 = *(const float2*)bias2[w],     b0 = *(const float2*)bias2[w + 2];
        float2 a1 = *(const float2*)bias2[w + 4], b1 = *(const float2*)bias2[w + 6];
        c0 = f32x4{a0.x, a0.y, b0.x, b0.y};
        c1 = f32x4{a1.x, a1.y, b1.x, b1.y};
      } else {
        c0 = csplat;
        c1 = csplat;
      }
      f32x4 s0 = __builtin_amdgcn_mfma_f32_16x16x32_bf16(
          kfC[0][1], qf[mi][1],
          __builtin_amdgcn_mfma_f32_16x16x32_bf16(kfC[0][0], qf[mi][0], c0, 0, 0, 0), 0, 0, 0);
      f32x4 s1 = __builtin_amdgcn_mfma_f32_16x16x32_bf16(
          kfC[1][1], qf[mi][1],
          __builtin_amdgcn_mfma_f32_16x16x32_bf16(kfC[1][0], qf[mi][0], c1, 0, 0, 0), 0, 0, 0);
      pfC[mi] =
          bf16x8{(bf16_t)__builtin_amdgcn_exp2f(s0[0]), (bf16_t)__builtin_amdgcn_exp2f(s0[1]),
                 (bf16_t)__builtin_amdgcn_exp2f(s0[2]), (bf16_t)__builtin_amdgcn_exp2f(s0[3]),
                 (bf16_t)__builtin_amdgcn_exp2f(s1[0]), (bf16_t)__builtin_amdgcn_exp2f(s1[1]),
                 (bf16_t)__builtin_amdgcn_exp2f(s1[2]), (bf16_t)__builtin_amdgcn_exp2f(s1[3])};
    }
  };

  bf16x8 kfA[2][2], vfA[4], kfB[2][2], vfB[4], pfA[4], pfB[4];
  loadK(0, kfA);
  loadV(0, vfA);
  __syncthreads();  // bias2 ready
  loadK(1, kfB);
  step0(kfA, pfA);      // QK(0) -> pfA
  loadV(1, vfB);

  for (int it = 1; it < 32; it += 2) {
    // odd it: cur = B buffers, prev = A
    if (it + 1 < 32) loadK(it + 1, kfA);   // kfA dead since QK(it-1)
    step(it, kfB, pfA, vfA, pfB);          // QK(it); PV(it-1) consumes vfA
    if (it + 1 < 32) {
      loadV(it + 1, vfA);                  // vfA dead now
      loadK(it + 2, kfB);                  // it+2 <= 31 whenever this branch runs
      step(it + 1, kfA, pfB, vfB, pfA);    // QK(it+1); PV(it) consumes vfB
      loadV(it + 2, vfB);
    }
  }
  // PV for the last tile (31): pfB produced by step(31), vfB holds vf(31)
#pragma unroll
  for (int mi = 0; mi < 4; mi++) {
#pragma unroll
    for (int ni = 0; ni < 4; ni++)
      accO[mi][ni] =
          __builtin_amdgcn_mfma_f32_16x16x32_bf16(vfB[ni], pfB[mi], accO[mi][ni], 0, 0, 0);
    accS[mi] = __builtin_amdgcn_mfma_f32_16x16x32_bf16(ones, pfB[mi], accS[mi], 0, 0, 0);
  }

  __syncthreads();
  if (kh) {
#pragma unroll
    for (int mi = 0; mi < 4; mi++) {
#pragma unroll
      for (int ni = 0; ni < 4; ni++)
        Ored[((qh * 4 + mi) * 4 + ni) * 64 + lane] = accO[mi][ni];
      if (quad == 0) OsumS[qh][mi][l15] = accS[mi][0];
    }
  }
  __syncthreads();
  if (!kh) {
#pragma unroll
    for (int mi = 0; mi < 4; mi++) {
      float l = accS[mi][0] + OsumS[qh][mi][l15];
      float inv = 1.0f / l;
      int srow = it0 + 64 * qh + mi * 16 + l15;
#pragma unroll
      for (int ni = 0; ni < 4; ni++) {
        f32x4 o = accO[mi][ni] + Ored[((qh * 4 + mi) * 4 + ni) * 64 + lane];
        bf16x4 pk = {(bf16_t)(o[0] * inv), (bf16_t)(o[1] * inv),
                     (bf16_t)(o[2] * inv), (bf16_t)(o[3] * inv)};
        *(bf16x4*)(&ctx[((size_t)(b * SS + srow)) * DM + h * DK + ni * 16 + quad * 4]) = pk;
      }
    }
  }
}

// ---------------- output projection: out = ctx @ Wo (fp32 out), m-panel-fastest grid ------
__global__ __launch_bounds__(256) void k_gemm_out(const bf16_t* __restrict__ A,
                                                  const bf16_t* __restrict__ Wot,
                                                  float* __restrict__ out) {
  __shared__ bf16_t As[128 * 32];
  __shared__ bf16_t Bs[128 * 32];
  const int m0 = blockIdx.x * 128, n0 = blockIdx.y * 128;
  f32x4 acc[4][4];
  gemm_tile(A, Wot, DM, m0, n0, As, Bs, acc);

  const int tid = threadIdx.x;
  const int lane = tid & 63, wave = tid >> 6;
  const int l15 = lane & 15, quad = lane >> 4;
  const int wm = (wave >> 1) * 64, wn = (wave & 1) * 64;
#pragma unroll
  for (int i = 0; i < 4; i++)
#pragma unroll
    for (int j = 0; j < 4; j++)
#pragma unroll
      for (int r = 0; r < 4; r++) {
        int m = m0 + wm + i * 16 + quad * 4 + r;
        int n = n0 + wn + j * 16 + l15;
        out[(size_t)m * DM + n] = acc[i][j][r];
      }
}

extern "C" void kernel_launch(void* const* d_in, const int* in_sizes, int n_in,
                              void* d_out, int out_size, void* d_ws, size_t ws_size,
                              hipStream_t stream) {
  (void)in_sizes; (void)n_in; (void)out_size; (void)ws_size;
  const float* H  = (const float*)d_in[0];
  const float* Wq = (const float*)d_in[1];
  const float* Wk = (const float*)d_in[2];
  const float* Wv = (const float*)d_in[3];
  const float* Wo = (const float*)d_in[4];
  const float* rel = (const float*)d_in[5];
  float* out = (float*)d_out;

  char* w = (char*)d_ws;
  bf16_t* Hbf = (bf16_t*)w; w += (size_t)MM * DM * 2;
  bf16_t* Wqt = (bf16_t*)w; w += (size_t)DM * DM * 2;   // fragment-major
  bf16_t* Wkt = (bf16_t*)w; w += (size_t)DM * DM * 2;   // fragment-major
  bf16_t* Wvt = (bf16_t*)w; w += (size_t)DM * DM * 2;   // fragment-major
  bf16_t* Wot = (bf16_t*)w; w += (size_t)DM * DM * 2;   // row-major [n][k]
  bf16_t* Q   = (bf16_t*)w; w += (size_t)MM * DM * 2;
  bf16_t* Kf  = (bf16_t*)w; w += (size_t)MM * DM * 2;
  bf16_t* Vf  = (bf16_t*)w; w += (size_t)MM * DM * 2;
  bf16_t* CTX = (bf16_t*)w; w += (size_t)MM * DM * 2;
  float* biasT = (float*)w;  // NH * 4095 floats

  k_prep<<<9232, 256, 0, stream>>>(H, Hbf, Wq, Wk, Wv, Wo, Wqt, Wkt, Wvt, Wot, rel, biasT);
  k_gemm_qkv<<<dim3(MM / 128, DM / 128, 3), 256, 0, stream>>>(Hbf, Wqt, Wkt, Wvt, Q, Kf, Vf);
  k_attn<<<dim3(SS / 128, NB * NH), 256, 0, stream>>>(Q, Kf, Vf, biasT, CTX);
  k_gemm_out<<<dim3(MM / 128, DM / 128), 256, 0, stream>>>(CTX, Wot, out);
}